// Round 7
// baseline (164.653 us; speedup 1.0000x reference)
//
#include <hip/hip_runtime.h>

// ALSTM: adaptive-computation-time LSTM (halts at t=1 for this data; exact
// for general n).
// R18: R17 datapath byte-identical (16 waves/CU, AGPR-held weights, no
// spill) + epoch-counter barrier. Theory: R16/R17's flat barrier has
// 65,536 pollers x 64B line every ~100cy = tens of TB/s of agent-scope
// poll traffic on the fabric, contending the straggler blocks' weight
// stream during exactly the window the barrier waits out. Evidence: dur
// invariant across occupancy 20->41% (R16 vs R17), queue-depth math rules
// out wave-side limits, poison fill sustains 6.3 TB/s unbarriered while
// our barriered stream gets 2.5 TB/s.
//  - ONE u64 epoch counter: tid0 atomic_fetch_add (relaxed, agent) after
//    vmcnt(0)-completed h publish; ONLY tid0 polls (256 pollers on one
//    line, ~1000x less poll traffic), s_sleep(4) backoff; __syncthreads
//    broadcasts release. Phase-monotone counter is race-free: no block
//    can increment epoch t+1 before all of epoch t arrived.
//  - No NT loads: warm-L3 half of the 109MB working set is worth keeping.

#define HID    2048
#define INS    1024
#define OUTS   1024
#define MSTEPS 100
#define NBLK   256
#define NTHR   1024
#define NWAVE  16
#define JPB    8      // hidden units owned per block (256*8 = 2048)
#define RPB    32     // gate rows per block (4 gates * JPB)
#define SLOTF  16     // floats per sync slot (64 B)

typedef unsigned long long u64;
typedef unsigned int u32;

__device__ __forceinline__ float wave_allreduce(float v) {
    #pragma unroll
    for (int off = 32; off > 0; off >>= 1)
        v += __shfl_xor(v, off, 64);
    return v;  // all lanes hold the sum
}

__device__ __forceinline__ u64 aload(const u64* p) {
    return __hip_atomic_load(p, __ATOMIC_RELAXED, __HIP_MEMORY_SCOPE_AGENT);
}
__device__ __forceinline__ void astoref(float* p, float v) {
    __hip_atomic_store(p, v, __ATOMIC_RELAXED, __HIP_MEMORY_SCOPE_AGENT);
}

// ws layout (floats): [0..2) epoch counter (u64) | [4096..6144) hbuf0 |
// [6144..8192) hbuf1.  kernel_launch zeroes 32768 bytes.

__global__
__attribute__((amdgpu_flat_work_group_size(NTHR, NTHR)))
__attribute__((amdgpu_waves_per_eu(4, 4)))
void alstm_kernel(
    const float* __restrict__ x,      const float* __restrict__ h0,
    const float* __restrict__ c0,     const float* __restrict__ W_ih,
    const float* __restrict__ b_ih,   const float* __restrict__ W_hh,
    const float* __restrict__ b_hh,   const float* __restrict__ w_halt,
    const float* __restrict__ b_halt, const float* __restrict__ W_out,
    const float* __restrict__ b_out,  float* __restrict__ out,
    float* __restrict__ ws)
{
    const int b    = blockIdx.x;
    const int tid  = threadIdx.x;
    const int wave = tid >> 6;
    const int lane = tid & 63;

    u64*   ectr  = (u64*)ws;            // single epoch counter
    float* hbuf0 = ws + NBLK * SLOTF;
    float* hbuf1 = hbuf0 + HID;

    __shared__ float x_lds[INS];          // 4 KB
    __shared__ float hjoint[HID];         // 8 KB: h0 (t=0 dot), hbar at end
    __shared__ float hcur[HID];           // 8 KB: h_t broadcast for matvec
    __shared__ float gate_lds[RPB];
    __shared__ float ihx_lds[RPB];
    __shared__ float psum[NWAVE];

    const int j_own = b * JPB + tid;      // valid when tid < JPB
    const int lr0   = 2 * wave;           // rows lr0, lr0+1 ; lr = gate*8+unit
    #define GR(lr_) (((lr_) >> 3) * HID + b * JPB + ((lr_) & 7))

    // W_hh@h dot: 2 register-resident rows vs a fp32 vector in LDS.
    #define DOT2(H4P, G0, G1) do {                                             \
        const float4* h4__ = (H4P);                                            \
        _Pragma("unroll")                                                      \
        for (int m = 0; m < 8; ++m) {                                          \
            float4 hh = h4__[lane + 64 * m];                                   \
            G0 += wa0[m].x*hh.x + wa0[m].y*hh.y + wa0[m].z*hh.z + wa0[m].w*hh.w; \
            G1 += wa1[m].x*hh.x + wa1[m].y*hh.y + wa1[m].z*hh.z + wa1[m].w*hh.w; \
        }                                                                      \
    } while (0)

    // ---------------- Group A: smalls (oldest in the queue) ----------------
    const float bh = b_halt[0];
    float  xv  = x[tid];                            // 1 float (INS = NTHR)
    float2 h0v = ((const float2*)h0)[tid];
    float2 wh2 = ((const float2*)w_halt)[tid];      // halt dot, per-thread
    float c_reg = (tid < JPB) ? c0[j_own] : 0.f;
    float bo    = (tid < 4)   ? b_out[b * 4 + tid] : 0.f;
    float bsum = 0.f, wflg = 0.f;
    if (lane < 2) {
        const int r = GR(lr0 + lane);
        bsum = b_ih[r] + b_hh[r];
        wflg = W_ih[(size_t)r * (INS + 1)];
    }
    __builtin_amdgcn_sched_barrier(0);

    // ---------------- Group B: W_ih 2 rows x 4 float4 ----------------
    const int rA = GR(lr0), rB = GR(lr0 + 1);
    const float* wrA = W_ih + (size_t)rA * (INS + 1) + 1;   // payload
    const float* wrB = W_ih + (size_t)rB * (INS + 1) + 1;
    const int pA = (4 - ((rA + 1) & 3)) & 3;
    const int pB = (4 - ((rB + 1) & 3)) & 3;
    const float4* wvA = (const float4*)(wrA + pA);
    const float4* wvB = (const float4*)(wrB + pB);
    float4 iwA[4], iwB[4];
    #pragma unroll
    for (int ii = 0; ii < 4; ++ii) {
        const int i  = lane + 64 * ii;
        const int ic = (i < 255) ? i : 0;   // clamp; masked at accumulate
        iwA[ii] = wvA[ic];
        iwB[ii] = wvB[ic];
    }
    __builtin_amdgcn_sched_barrier(0);

    // stage x + h0 (waits only on Group A; B stays in flight)
    x_lds[tid] = xv;
    ((float2*)hjoint)[tid] = h0v;        // hjoint = fp32 h0 for fused t=0 dot
    __syncthreads();

    // ---- x-dots: W_ih[:,1:]@x, 2 rows (consumes B; iw regs die here) ----
    float a0 = 0.f, a1 = 0.f;
    #pragma unroll
    for (int ii = 0; ii < 4; ++ii) {
        const int   i   = lane + 64 * ii;
        const int   ic  = (i < 255) ? i : 0;
        const float msk = (i < 255) ? 1.f : 0.f;
        {
            const int k = pA + 4 * ic;
            a0 += msk * (iwA[ii].x * x_lds[k]     + iwA[ii].y * x_lds[k + 1]
                       + iwA[ii].z * x_lds[k + 2] + iwA[ii].w * x_lds[k + 3]);
        }
        {
            const int k = pB + 4 * ic;
            a1 += msk * (iwB[ii].x * x_lds[k]     + iwB[ii].y * x_lds[k + 1]
                       + iwB[ii].z * x_lds[k + 2] + iwB[ii].w * x_lds[k + 3]);
        }
    }
    if (lane < 4) {   // leftover 4 elements per row
        const int eA = (lane < pA) ? lane : 1020 + lane;
        const int eB = (lane < pB) ? lane : 1020 + lane;
        a0 += wrA[eA] * x_lds[eA];
        a1 += wrB[eB] * x_lds[eB];
    }

    // ------- Group C: W_hh 2 rows x 8 float4 -> registers (64 VGPR) -------
    float4 wa0[8], wa1[8];
    {
        const float4* s0 = (const float4*)(W_hh + (size_t)rA * HID);
        const float4* s1 = (const float4*)(W_hh + (size_t)rB * HID);
        #pragma unroll
        for (int m = 0; m < 8; ++m) {
            wa0[m] = s0[lane + 64 * m];
            wa1[m] = s1[lane + 64 * m];
        }
    }
    // ------- Group D: W_out 2 float4 (quarter-row per wave) -> registers ---
    const int orow = b * 4 + (wave & 3);
    const int oq   = wave >> 2;
    const float4* wrow = (const float4*)(W_out + (size_t)orow * HID) + oq * 128;
    float4 wo0 = wrow[lane], wo1 = wrow[lane + 64];
    __builtin_amdgcn_sched_barrier(0);

    // ---- t=0 gate dots: register W_hh vs fp32 h0 (consumes C; D in flight) --
    float g0 = 0.f, g1 = 0.f;
    DOT2((const float4*)hjoint, g0, g1);

    a0 = wave_allreduce(a0); a1 = wave_allreduce(a1);
    g0 = wave_allreduce(g0); g1 = wave_allreduce(g1);
    if (lane < 2) {
        float av = lane ? a1 : a0;
        float gv = lane ? g1 : g0;
        ihx_lds[lr0 + lane]  = av + bsum;                // reused every step
        gate_lds[lr0 + lane] = av + bsum + wflg + gv;    // t=0 gates (flag=1)
    }
    __syncthreads();                       // gate_lds ready

    // ------------- recurrence: epoch-counter barrier per step -------------
    float2 hb2 = make_float2(0.f, 0.f);    // hbar (per-thread slot)
    float  h_reg = 0.f, cbar = 0.f, csum = 0.f, r_halt = 0.f;
    int    n_halt = 0;
    for (int t = 0; t <= MSTEPS; ++t) {
        // ---- unit update: own 8 units; publish via agent-scope atomics ----
        float* hdst = (t & 1) ? hbuf1 : hbuf0;
        if (tid < JPB) {
            float iv = gate_lds[0 * JPB + tid];
            float fv = gate_lds[1 * JPB + tid];
            float gv = gate_lds[2 * JPB + tid];
            float ov = gate_lds[3 * JPB + tid];
            iv = 1.f / (1.f + expf(-iv));
            fv = 1.f / (1.f + expf(-fv));
            gv = tanhf(gv);
            ov = 1.f / (1.f + expf(-ov));
            c_reg = fv * c_reg + iv * gv;
            h_reg = ov * tanhf(c_reg);
            astoref(hdst + j_own, h_reg);     // write-through to coherence pt
        }
        asm volatile("s_waitcnt vmcnt(0)" ::: "memory");  // h stores complete
        if (tid == 0)
            __hip_atomic_fetch_add(ectr, 1ull, __ATOMIC_RELAXED,
                                   __HIP_MEMORY_SCOPE_AGENT);

        // ---- barrier: ONLY tid0 polls the single counter line ----
        if (tid == 0) {
            const u64 target = (u64)NBLK * (u64)(t + 1);
            u64 v = aload(ectr);
            while (v < target) {
                __builtin_amdgcn_s_sleep(4);
                v = aload(ectr);
            }
        }
        __syncthreads();                 // release whole block

        // ---- read full H[t] via agent-scope atomic loads (bypass L2) ----
        const u64* hsrc = (const u64*)((t & 1) ? hbuf1 : hbuf0);
        u64 hA = aload(hsrc + tid);
        float2 hv = make_float2(__uint_as_float((u32)hA),
                                __uint_as_float((u32)(hA >> 32)));
        ((float2*)hcur)[tid] = hv;

        // ---- halt dot: redundant per block, fixed order -> uniform ----
        float part = hv.x * wh2.x + hv.y * wh2.y;
        part = wave_allreduce(part);
        if (lane == 0) psum[wave] = part;
        __syncthreads();                 // hcur + psum ready
        float dotv = (((psum[0]  + psum[1])  + (psum[2]  + psum[3]))
                   +  ((psum[4]  + psum[5])  + (psum[6]  + psum[7])))
                   + (((psum[8]  + psum[9])  + (psum[10] + psum[11]))
                   +  ((psum[12] + psum[13]) + (psum[14] + psum[15])));
        float p = 1.f / (1.f + expf(-(dotv + bh)));
        float prev = csum;
        csum += p;
        bool  halt_now = (csum >= 1.f - 0.01f) || (t == MSTEPS);
        float wt = halt_now ? (1.f - prev) : p;
        hb2.x += wt * hv.x; hb2.y += wt * hv.y;
        if (tid < JPB) cbar += wt * c_reg;
        if (halt_now) { n_halt = t; r_halt = 1.f - prev; break; }  // uniform

        // ---- gates for step t+1: register W_hh vs fp32 hcur ----
        {
            float m0 = 0.f, m1 = 0.f;
            DOT2((const float4*)hcur, m0, m1);
            m0 = wave_allreduce(m0);
            m1 = wave_allreduce(m1);
            if (lane < 2)
                gate_lds[lr0 + lane] = ihx_lds[lr0 + lane] + (lane ? m1 : m0);
        }
        __syncthreads();                 // gate_lds ready for next t
    }

    // ------------- epilogue (no grid sync) -------------
    ((float2*)hjoint)[tid] = hb2;                     // stage hbar for W_out
    if (b == 0) ((float2*)(out + OUTS))[tid] = hb2;   // h_out (identical in
                                                      //  all blocks)
    if (tid < JPB) out[OUTS + HID + j_own] = cbar;    // c_out (own units)
    if (b == 0 && tid == 0) out[OUTS + 2 * HID] = (float)(n_halt + 1) + r_halt;
    __syncthreads();                                  // hjoint ready

    // output = W_out @ hbar + b_out : quarter-rows already in registers
    {
        const float4* hb4p = (const float4*)hjoint + oq * 128;
        float acc = 0.f;
        { float4 h4 = hb4p[lane];      acc += wo0.x*h4.x + wo0.y*h4.y + wo0.z*h4.z + wo0.w*h4.w; }
        { float4 h4 = hb4p[lane + 64]; acc += wo1.x*h4.x + wo1.y*h4.y + wo1.z*h4.z + wo1.w*h4.w; }
        acc = wave_allreduce(acc);
        if (lane == 0) psum[wave] = acc;
    }
    __syncthreads();
    if (tid < 4)
        out[b * 4 + tid] = psum[tid] + psum[tid + 4] + psum[tid + 8]
                         + psum[tid + 12] + bo;

    #undef DOT2
    #undef GR
}

extern "C" void kernel_launch(void* const* d_in, const int* in_sizes, int n_in,
                              void* d_out, int out_size, void* d_ws, size_t ws_size,
                              hipStream_t stream) {
    const float* x      = (const float*)d_in[0];
    const float* h0     = (const float*)d_in[1];
    const float* c0     = (const float*)d_in[2];
    const float* W_ih   = (const float*)d_in[3];
    const float* b_ih   = (const float*)d_in[4];
    const float* W_hh   = (const float*)d_in[5];
    const float* b_hh   = (const float*)d_in[6];
    const float* w_halt = (const float*)d_in[7];
    const float* b_halt = (const float*)d_in[8];
    const float* W_out  = (const float*)d_in[9];
    const float* b_out  = (const float*)d_in[10];
    float* out = (float*)d_out;
    float* ws  = (float*)d_ws;

    // Zero epoch counter + hbufs. ws is poisoned 0xAA by the harness.
    hipMemsetAsync(d_ws, 0, 32768, stream);

    alstm_kernel<<<dim3(NBLK), dim3(NTHR), 0, stream>>>(
        x, h0, c0, W_ih, b_ih, W_hh, b_hh, w_halt, b_halt, W_out, b_out,
        out, ws);
}

// Round 8
// 153.444 us; speedup vs baseline: 1.0730x; 1.0730x over previous
//
#include <hip/hip_runtime.h>

// ALSTM: adaptive-computation-time LSTM (halts at t=1 for this data; exact
// for general n).
// R19: R17 verbatim (best measured: 43.5us kernel) + NON-TEMPORAL weight
// loads. Theory: the harness's 268MB poison fill leaves the 256MB MALL
// full of dirty lines; our 109MB weight-read misses allocate -> evict
// dirty poison -> ~109MB HBM writeback ON OUR CRITICAL PATH. 109r+109w
// at 6.3TB/s = 35us + syncs = the 43us floor seen in R12/R16/R17.
// nt loads (no cache allocation) skip the eviction entirely; the poison
// lines get overwritten in place by the NEXT fill (that writeback never
// happens). Weights have zero reuse - textbook NT.
// (Also: FETCH_SIZE undercounts ~2x on gfx950 - 54MB reported vs 109MB
// known unique bytes; gfx94x formula fallback. Trust byte arithmetic.)
// R18 post-mortem: epoch-counter barrier slightly WORSE (serialized
// fetch-add); reverted to R17's flat per-slot barrier.

#define HID    2048
#define INS    1024
#define OUTS   1024
#define MSTEPS 100
#define NBLK   256
#define NTHR   1024
#define NWAVE  16
#define JPB    8      // hidden units owned per block (256*8 = 2048)
#define RPB    32     // gate rows per block (4 gates * JPB)
#define SLOTF  16     // floats per sync slot (64 B)

typedef unsigned long long u64;
typedef unsigned int u32;
typedef float f32x4 __attribute__((ext_vector_type(4)));

__device__ __forceinline__ float wave_allreduce(float v) {
    #pragma unroll
    for (int off = 32; off > 0; off >>= 1)
        v += __shfl_xor(v, off, 64);
    return v;  // all lanes hold the sum
}

__device__ __forceinline__ u64 aload(const u64* p) {
    return __hip_atomic_load(p, __ATOMIC_RELAXED, __HIP_MEMORY_SCOPE_AGENT);
}
__device__ __forceinline__ void astore(u64* p, u64 v) {
    __hip_atomic_store(p, v, __ATOMIC_RELAXED, __HIP_MEMORY_SCOPE_AGENT);
}
__device__ __forceinline__ void astoref(float* p, float v) {
    __hip_atomic_store(p, v, __ATOMIC_RELAXED, __HIP_MEMORY_SCOPE_AGENT);
}

// nt float4 load: global_load_dwordx4 ... nt (no cache allocation)
__device__ __forceinline__ float4 ntld4(const float4* p) {
    f32x4 v = __builtin_nontemporal_load((const f32x4*)p);
    return make_float4(v.x, v.y, v.z, v.w);
}
__device__ __forceinline__ float ntld1(const float* p) {
    return __builtin_nontemporal_load(p);
}

// ws layout (floats): [0..4096) arrive slots (256 x 64B) | [4096..6144)
// hbuf0 | [6144..8192) hbuf1.  kernel_launch zeroes 32768 bytes.

__global__
__attribute__((amdgpu_flat_work_group_size(NTHR, NTHR)))
__attribute__((amdgpu_waves_per_eu(4, 4)))
void alstm_kernel(
    const float* __restrict__ x,      const float* __restrict__ h0,
    const float* __restrict__ c0,     const float* __restrict__ W_ih,
    const float* __restrict__ b_ih,   const float* __restrict__ W_hh,
    const float* __restrict__ b_hh,   const float* __restrict__ w_halt,
    const float* __restrict__ b_halt, const float* __restrict__ W_out,
    const float* __restrict__ b_out,  float* __restrict__ out,
    float* __restrict__ ws)
{
    const int b    = blockIdx.x;
    const int tid  = threadIdx.x;
    const int wave = tid >> 6;
    const int lane = tid & 63;

    float* arrive = ws;                 // 256 x SLOTF floats (u64 counters)
    float* hbuf0  = ws + NBLK * SLOTF;
    float* hbuf1  = hbuf0 + HID;

    __shared__ float x_lds[INS];          // 4 KB
    __shared__ float hjoint[HID];         // 8 KB: h0 (t=0 dot), hbar at end
    __shared__ float hcur[HID];           // 8 KB: h_t broadcast for matvec
    __shared__ float gate_lds[RPB];
    __shared__ float ihx_lds[RPB];
    __shared__ float psum[NWAVE];

    const int j_own = b * JPB + tid;      // valid when tid < JPB
    const int lr0   = 2 * wave;           // rows lr0, lr0+1 ; lr = gate*8+unit
    #define GR(lr_) (((lr_) >> 3) * HID + b * JPB + ((lr_) & 7))

    // W_hh@h dot: 2 register-resident rows vs a fp32 vector in LDS.
    #define DOT2(H4P, G0, G1) do {                                             \
        const float4* h4__ = (H4P);                                            \
        _Pragma("unroll")                                                      \
        for (int m = 0; m < 8; ++m) {                                          \
            float4 hh = h4__[lane + 64 * m];                                   \
            G0 += wa0[m].x*hh.x + wa0[m].y*hh.y + wa0[m].z*hh.z + wa0[m].w*hh.w; \
            G1 += wa1[m].x*hh.x + wa1[m].y*hh.y + wa1[m].z*hh.z + wa1[m].w*hh.w; \
        }                                                                      \
    } while (0)

    // ---------------- Group A: smalls (oldest in the queue) ----------------
    const float bh = b_halt[0];
    float  xv  = x[tid];                            // 1 float (INS = NTHR)
    float2 h0v = ((const float2*)h0)[tid];
    float2 wh2 = ((const float2*)w_halt)[tid];      // halt dot, per-thread
    float c_reg = (tid < JPB) ? c0[j_own] : 0.f;
    float bo    = (tid < 4)   ? b_out[b * 4 + tid] : 0.f;
    float bsum = 0.f, wflg = 0.f;
    if (lane < 2) {
        const int r = GR(lr0 + lane);
        bsum = b_ih[r] + b_hh[r];
        wflg = W_ih[(size_t)r * (INS + 1)];
    }
    __builtin_amdgcn_sched_barrier(0);

    // ------------ Group B: W_ih 2 rows x 4 float4 (NT stream) ------------
    const int rA = GR(lr0), rB = GR(lr0 + 1);
    const float* wrA = W_ih + (size_t)rA * (INS + 1) + 1;   // payload
    const float* wrB = W_ih + (size_t)rB * (INS + 1) + 1;
    const int pA = (4 - ((rA + 1) & 3)) & 3;
    const int pB = (4 - ((rB + 1) & 3)) & 3;
    const float4* wvA = (const float4*)(wrA + pA);
    const float4* wvB = (const float4*)(wrB + pB);
    float4 iwA[4], iwB[4];
    #pragma unroll
    for (int ii = 0; ii < 4; ++ii) {
        const int i  = lane + 64 * ii;
        const int ic = (i < 255) ? i : 0;   // clamp; masked at accumulate
        iwA[ii] = ntld4(wvA + ic);
        iwB[ii] = ntld4(wvB + ic);
    }
    __builtin_amdgcn_sched_barrier(0);

    // stage x + h0 (waits only on Group A; B stays in flight)
    x_lds[tid] = xv;
    ((float2*)hjoint)[tid] = h0v;        // hjoint = fp32 h0 for fused t=0 dot
    __syncthreads();

    // ---- x-dots: W_ih[:,1:]@x, 2 rows (consumes B; iw regs die here) ----
    float a0 = 0.f, a1 = 0.f;
    #pragma unroll
    for (int ii = 0; ii < 4; ++ii) {
        const int   i   = lane + 64 * ii;
        const int   ic  = (i < 255) ? i : 0;
        const float msk = (i < 255) ? 1.f : 0.f;
        {
            const int k = pA + 4 * ic;
            a0 += msk * (iwA[ii].x * x_lds[k]     + iwA[ii].y * x_lds[k + 1]
                       + iwA[ii].z * x_lds[k + 2] + iwA[ii].w * x_lds[k + 3]);
        }
        {
            const int k = pB + 4 * ic;
            a1 += msk * (iwB[ii].x * x_lds[k]     + iwB[ii].y * x_lds[k + 1]
                       + iwB[ii].z * x_lds[k + 2] + iwB[ii].w * x_lds[k + 3]);
        }
    }
    if (lane < 4) {   // leftover 4 elements per row (NT scalar)
        const int eA = (lane < pA) ? lane : 1020 + lane;
        const int eB = (lane < pB) ? lane : 1020 + lane;
        a0 += ntld1(wrA + eA) * x_lds[eA];
        a1 += ntld1(wrB + eB) * x_lds[eB];
    }

    // ---- Group C: W_hh 2 rows x 8 float4 -> registers (NT stream) ----
    float4 wa0[8], wa1[8];
    {
        const float4* s0 = (const float4*)(W_hh + (size_t)rA * HID);
        const float4* s1 = (const float4*)(W_hh + (size_t)rB * HID);
        #pragma unroll
        for (int m = 0; m < 8; ++m) {
            wa0[m] = ntld4(s0 + lane + 64 * m);
            wa1[m] = ntld4(s1 + lane + 64 * m);
        }
    }
    // ---- Group D: W_out 2 float4 (quarter-row per wave, NT stream) ----
    const int orow = b * 4 + (wave & 3);
    const int oq   = wave >> 2;
    const float4* wrow = (const float4*)(W_out + (size_t)orow * HID) + oq * 128;
    float4 wo0 = ntld4(wrow + lane), wo1 = ntld4(wrow + lane + 64);
    __builtin_amdgcn_sched_barrier(0);

    // ---- t=0 gate dots: register W_hh vs fp32 h0 (consumes C; D in flight) --
    float g0 = 0.f, g1 = 0.f;
    DOT2((const float4*)hjoint, g0, g1);

    a0 = wave_allreduce(a0); a1 = wave_allreduce(a1);
    g0 = wave_allreduce(g0); g1 = wave_allreduce(g1);
    if (lane < 2) {
        float av = lane ? a1 : a0;
        float gv = lane ? g1 : g0;
        ihx_lds[lr0 + lane]  = av + bsum;                // reused every step
        gate_lds[lr0 + lane] = av + bsum + wflg + gv;    // t=0 gates (flag=1)
    }
    __syncthreads();                       // gate_lds ready

    // ------------- recurrence: ONE flat fence-free round per step ---------
    float2 hb2 = make_float2(0.f, 0.f);    // hbar (per-thread slot)
    float  h_reg = 0.f, cbar = 0.f, csum = 0.f, r_halt = 0.f;
    int    n_halt = 0;
    for (int t = 0; t <= MSTEPS; ++t) {
        // ---- unit update: own 8 units; publish via agent-scope atomics ----
        float* hdst = (t & 1) ? hbuf1 : hbuf0;
        if (tid < JPB) {
            float iv = gate_lds[0 * JPB + tid];
            float fv = gate_lds[1 * JPB + tid];
            float gv = gate_lds[2 * JPB + tid];
            float ov = gate_lds[3 * JPB + tid];
            iv = 1.f / (1.f + expf(-iv));
            fv = 1.f / (1.f + expf(-fv));
            gv = tanhf(gv);
            ov = 1.f / (1.f + expf(-ov));
            c_reg = fv * c_reg + iv * gv;
            h_reg = ov * tanhf(c_reg);
            astoref(hdst + j_own, h_reg);     // write-through to coherence pt
        }
        asm volatile("s_waitcnt vmcnt(0)" ::: "memory");  // h stores done
        if (tid == 0)
            astore((u64*)(arrive + SLOTF * b), (u64)(t + 1));

        // ---- flat barrier: poll all 256 arrive counters ----
        if (tid < NBLK) {
            const u64* slot = (const u64*)(arrive + SLOTF * tid);
            u64 v = aload(slot);
            while (v < (u64)(t + 1)) {
                __builtin_amdgcn_s_sleep(1);
                v = aload(slot);
            }
        }
        __syncthreads();

        // ---- read full H[t] via agent-scope atomic loads (bypass L2) ----
        const u64* hsrc = (const u64*)((t & 1) ? hbuf1 : hbuf0);
        u64 hA = aload(hsrc + tid);
        float2 hv = make_float2(__uint_as_float((u32)hA),
                                __uint_as_float((u32)(hA >> 32)));
        ((float2*)hcur)[tid] = hv;

        // ---- halt dot: redundant per block, fixed order -> uniform ----
        float part = hv.x * wh2.x + hv.y * wh2.y;
        part = wave_allreduce(part);
        if (lane == 0) psum[wave] = part;
        __syncthreads();                 // hcur + psum ready
        float dotv = (((psum[0]  + psum[1])  + (psum[2]  + psum[3]))
                   +  ((psum[4]  + psum[5])  + (psum[6]  + psum[7])))
                   + (((psum[8]  + psum[9])  + (psum[10] + psum[11]))
                   +  ((psum[12] + psum[13]) + (psum[14] + psum[15])));
        float p = 1.f / (1.f + expf(-(dotv + bh)));
        float prev = csum;
        csum += p;
        bool  halt_now = (csum >= 1.f - 0.01f) || (t == MSTEPS);
        float wt = halt_now ? (1.f - prev) : p;
        hb2.x += wt * hv.x; hb2.y += wt * hv.y;
        if (tid < JPB) cbar += wt * c_reg;
        if (halt_now) { n_halt = t; r_halt = 1.f - prev; break; }  // uniform

        // ---- gates for step t+1: register W_hh vs fp32 hcur ----
        {
            float m0 = 0.f, m1 = 0.f;
            DOT2((const float4*)hcur, m0, m1);
            m0 = wave_allreduce(m0);
            m1 = wave_allreduce(m1);
            if (lane < 2)
                gate_lds[lr0 + lane] = ihx_lds[lr0 + lane] + (lane ? m1 : m0);
        }
        __syncthreads();                 // gate_lds ready for next t
    }

    // ------------- epilogue (no grid sync) -------------
    ((float2*)hjoint)[tid] = hb2;                     // stage hbar for W_out
    if (b == 0) ((float2*)(out + OUTS))[tid] = hb2;   // h_out (identical in
                                                      //  all blocks)
    if (tid < JPB) out[OUTS + HID + j_own] = cbar;    // c_out (own units)
    if (b == 0 && tid == 0) out[OUTS + 2 * HID] = (float)(n_halt + 1) + r_halt;
    __syncthreads();                                  // hjoint ready

    // output = W_out @ hbar + b_out : quarter-rows already in registers
    {
        const float4* hb4p = (const float4*)hjoint + oq * 128;
        float acc = 0.f;
        { float4 h4 = hb4p[lane];      acc += wo0.x*h4.x + wo0.y*h4.y + wo0.z*h4.z + wo0.w*h4.w; }
        { float4 h4 = hb4p[lane + 64]; acc += wo1.x*h4.x + wo1.y*h4.y + wo1.z*h4.z + wo1.w*h4.w; }
        acc = wave_allreduce(acc);
        if (lane == 0) psum[wave] = acc;
    }
    __syncthreads();
    if (tid < 4)
        out[b * 4 + tid] = psum[tid] + psum[tid + 4] + psum[tid + 8]
                         + psum[tid + 12] + bo;

    #undef DOT2
    #undef GR
}

extern "C" void kernel_launch(void* const* d_in, const int* in_sizes, int n_in,
                              void* d_out, int out_size, void* d_ws, size_t ws_size,
                              hipStream_t stream) {
    const float* x      = (const float*)d_in[0];
    const float* h0     = (const float*)d_in[1];
    const float* c0     = (const float*)d_in[2];
    const float* W_ih   = (const float*)d_in[3];
    const float* b_ih   = (const float*)d_in[4];
    const float* W_hh   = (const float*)d_in[5];
    const float* b_hh   = (const float*)d_in[6];
    const float* w_halt = (const float*)d_in[7];
    const float* b_halt = (const float*)d_in[8];
    const float* W_out  = (const float*)d_in[9];
    const float* b_out  = (const float*)d_in[10];
    float* out = (float*)d_out;
    float* ws  = (float*)d_ws;

    // Zero arrive slots (+slack). ws is poisoned 0xAA by the harness.
    hipMemsetAsync(d_ws, 0, 32768, stream);

    alstm_kernel<<<dim3(NBLK), dim3(NTHR), 0, stream>>>(
        x, h0, c0, W_ih, b_ih, W_hh, b_hh, w_halt, b_halt, W_out, b_out,
        out, ws);
}